// Round 5
// baseline (230.540 us; speedup 1.0000x reference)
//
#include <hip/hip_runtime.h>
#include <hip/hip_bf16.h>

#define NB 16
#define NS 2048
#define ND 768
#define NG 1024
#define ROWS (NB * NG)            // 16384 output rows (b*G + g)

#define BM 64
#define BN 256
#define BK 32
#define NCOL (ND / BN)            // 3 col-strips
#define NROW (ROWS / BM)          // 256 row-bands

typedef __attribute__((ext_vector_type(8))) __bf16 bf16x8;
typedef __attribute__((ext_vector_type(8))) unsigned short ushort8_t;
typedef __attribute__((ext_vector_type(4))) float f32x4;

__device__ __forceinline__ unsigned short f2bf(float f) {
    unsigned int u = __builtin_bit_cast(unsigned int, f);
    return (unsigned short)((u + 0x7FFFu + ((u >> 16) & 1u)) >> 16);   // RNE
}

__device__ __forceinline__ void gload_lds16(const void* g, void* l) {
    __builtin_amdgcn_global_load_lds((const __attribute__((address_space(1))) unsigned int*)g,
                                     (__attribute__((address_space(3))) unsigned int*)l, 16, 0, 0);
}

__device__ __forceinline__ float fast_tanh(float v) {
    float x = fminf(fmaxf(v, -15.f), 15.f);
    float e = __expf(2.f * x);
    return (e - 1.f) / (e + 1.f);
}

// ---- transpose-cast 0.5*W (768x768 f32 row-major [k][n]) to bf16 [n][k]
__global__ __launch_bounds__(256) void wtrans_kernel(const float* __restrict__ W,
                                                     unsigned short* __restrict__ Bt) {
    __shared__ float tile[64][65];
    int n0 = blockIdx.x * 64;
    int k0 = blockIdx.y * 64;
    int tx = threadIdx.x & 63;
    int ty = threadIdx.x >> 6;    // 0..3
    #pragma unroll
    for (int i = 0; i < 64; i += 4)
        tile[ty + i][tx] = W[(long)(k0 + ty + i) * ND + n0 + tx];
    __syncthreads();
    #pragma unroll
    for (int i = 0; i < 64; i += 4)
        Bt[(long)(n0 + ty + i) * ND + k0 + tx] = f2bf(0.5f * tile[tx][ty + i]);
}

// ---- fused GEMM: out[g][c] = tanh( sum_k (x[2g][k]+x[2g+1][k]) * (0.5*W)[k][c] + b[c] )
// BM=64 x BN=256, BK=32; 4 waves in 1x4 grid, wave tile 64x64 = 4x4 frags of 16x16x32.
// LDS holds tiles in FRAGMENT-LANE ORDER: 16x32 subtile = 1024B, lane l -> row l&15,
// k-slot l>>4. All ds_read_b128 / ds_write_b128 / gload_lds are dense contiguous
// per wave -> zero bank conflicts. B source per-lane permuted (gload_lds dest linear).
__global__ __launch_bounds__(256, 3) void gemm_fused_kernel(const float* __restrict__ x,
                                                            const unsigned short* __restrict__ Bt,
                                                            const float* __restrict__ bias,
                                                            float* __restrict__ out) {
    __shared__ unsigned short Al[BM * BK];   // 4 KB  = 4 subtiles
    __shared__ unsigned short Bl[BN * BK];   // 16 KB = 16 subtiles
    int tid = threadIdx.x;
    int lane = tid & 63;
    int w = tid >> 6;                        // wave = col strip within block
    int r = lane & 15, h = lane >> 4;

    // bijective XCD swizzle: xcd = bid&7; each XCD gets bands {xcd, xcd+8,...}, 3 strips each
    int bid = blockIdx.x;                    // 0..767
    int xcd = bid & 7;
    int s = bid >> 3;                        // 0..95
    int c = s % 3;
    int rb = (s / 3) * 8 + xcd;              // 0..255
    int row0 = rb * BM;
    int col0 = c * BN;

    int b = row0 >> 10;
    long tokrow = (long)b * NS + 2 * (row0 & (NG - 1));

    // ---- A staging (fragment order): thread t supplies LDS bytes [t*16, t*16+16):
    //   subtile w, lane l=t&63 -> group row w*16 + (l&15), k-slot (l>>4)*8
    int ag = w * 16 + r;
    const float* ax0 = x + (tokrow + 2 * ag) * ND + h * 8;
    const float* ax1 = ax0 + ND;
    char* alw = (char*)Al + tid * 16;

    // ---- B staging (fragment order): 4 sections q; dest byte = q*4096 + t*16
    //   subtile sB = q*4 + w, row = sB*16 + (l&15), k-slot l>>4
    const char* gBbase = (const char*)Bt + (long)(col0 + w * 16 + r) * (ND * 2) + h * 16;
    char* lB = (char*)Bl + tid * 16;

    float4 a0, a1, b0, b1;
    a0 = *(const float4*)ax0;  b0 = *(const float4*)(ax0 + 4);
    a1 = *(const float4*)ax1;  b1 = *(const float4*)(ax1 + 4);

    f32x4 acc[4][4] = {};

    for (int k0 = 0; k0 < ND; k0 += BK) {
        // B tile for this step (async, dense LDS dest; source row = col0+q*64+w*16+r)
        #pragma unroll
        for (int q = 0; q < 4; ++q)
            gload_lds16(gBbase + (long)q * 64 * (ND * 2) + k0 * 2, lB + q * 4096);
        // A: pair-sum + bf16, one dense 16B write
        ushort8_t aw;
        #pragma unroll
        for (int e = 0; e < 4; ++e) {
            aw[e]     = f2bf(a0[e] + a1[e]);
            aw[4 + e] = f2bf(b0[e] + b1[e]);
        }
        *(ushort8_t*)alw = aw;
        __syncthreads();                     // drains B gloads + A ds_writes

        // prefetch NEXT step's A inputs; they fly under the MFMA phase (T14)
        int adv = (k0 + BK < ND) ? BK : 0;
        ax0 += adv; ax1 += adv;
        a0 = *(const float4*)ax0;  b0 = *(const float4*)(ax0 + 4);
        a1 = *(const float4*)ax1;  b1 = *(const float4*)(ax1 + 4);

        // fragments: dense reads at lane*16 within each 1KB subtile
        bf16x8 af[4];
        #pragma unroll
        for (int m = 0; m < 4; ++m)
            af[m] = __builtin_bit_cast(bf16x8, *(const ushort8_t*)((const char*)Al + m * 1024 + lane * 16));
        #pragma unroll
        for (int n = 0; n < 4; ++n) {
            bf16x8 bfv = __builtin_bit_cast(bf16x8, *(const ushort8_t*)((const char*)Bl + (w * 4 + n) * 1024 + lane * 16));
            #pragma unroll
            for (int m = 0; m < 4; ++m)
                acc[m][n] = __builtin_amdgcn_mfma_f32_16x16x32_bf16(af[m], bfv, acc[m][n], 0, 0, 0);
        }
        __syncthreads();
    }

    float bv[4];
    #pragma unroll
    for (int n = 0; n < 4; ++n) bv[n] = bias[col0 + w * 64 + n * 16 + r];

    #pragma unroll
    for (int m = 0; m < 4; ++m) {
        #pragma unroll
        for (int q = 0; q < 4; ++q) {
            int orow = row0 + m * 16 + h * 4 + q;
            float* op = out + (long)orow * ND + col0 + w * 64 + r;
            #pragma unroll
            for (int n = 0; n < 4; ++n)
                op[n * 16] = fast_tanh(acc[m][n][q] + bv[n]);
        }
    }
}

// ---- per-group masks + per-block partial sums (no atomics, no pre-zero)
__global__ __launch_bounds__(256) void masks_kernel(const int* __restrict__ padding,
                                                    const int* __restrict__ regular,
                                                    const int* __restrict__ seqpair,
                                                    float* __restrict__ out_mp,
                                                    float* __restrict__ out_mr,
                                                    float* __restrict__ out_ms,
                                                    int2* __restrict__ partials) {
    int i = blockIdx.x * 256 + threadIdx.x;      // over ROWS
    int b = i >> 10, g = i & (NG - 1);
    int t = b * NS + 2 * g;
    int r0 = regular[t], r1 = regular[t + 1];
    int p  = ((padding[t] | padding[t + 1]) != 0) ? 1 : 0;
    int mr = ((r0 | r1) != 0) ? 1 : 0;
    int ms = ((seqpair[t] > 0) && (seqpair[t + 1] > 0)) ? 1 : 0;
    if (p == 0) ms = -1;
    out_mp[i] = (float)p;
    out_mr[i] = (float)mr;
    out_ms[i] = (float)ms;

    int mrs = mr, tok = r0 + r1;
    #pragma unroll
    for (int off = 32; off > 0; off >>= 1) {
        mrs += __shfl_down(mrs, off);
        tok += __shfl_down(tok, off);
    }
    __shared__ int sm[4], st[4];
    int wv = threadIdx.x >> 6, lane = threadIdx.x & 63;
    if (lane == 0) { sm[wv] = mrs; st[wv] = tok; }
    __syncthreads();
    if (threadIdx.x == 0)
        partials[blockIdx.x] = make_int2(sm[0] + sm[1] + sm[2] + sm[3],
                                         st[0] + st[1] + st[2] + st[3]);
}

// ---- compression_rate from 64 per-block partials (single wave)
__global__ void cr_kernel(const int2* __restrict__ partials, float* __restrict__ cr) {
    int2 p = partials[threadIdx.x];
    int a = p.x, t = p.y;
    #pragma unroll
    for (int off = 32; off > 0; off >>= 1) {
        a += __shfl_down(a, off);
        t += __shfl_down(t, off);
    }
    if (threadIdx.x == 0) cr[0] = (float)a / (float)t;
}

extern "C" void kernel_launch(void* const* d_in, const int* in_sizes, int n_in,
                              void* d_out, int out_size, void* d_ws, size_t ws_size,
                              hipStream_t stream) {
    const float* x        = (const float*)d_in[0];
    const int*   padding  = (const int*)d_in[2];
    const int*   regular  = (const int*)d_in[3];
    const int*   seqpair  = (const int*)d_in[4];
    const float* W        = (const float*)d_in[6];
    const float* bias     = (const float*)d_in[7];

    float* outc   = (float*)d_out;                       // compact (B,G,D)
    float* out_mp = outc + (long)ROWS * ND;              // mask_padding (B,G)
    float* out_mr = out_mp + ROWS;                       // mask_regular (B,G)
    float* out_ms = out_mr + ROWS;                       // mask_seq_pair (B,G)
    float* out_cr = out_ms + ROWS;                       // compression_rate (1)

    unsigned short* wbt = (unsigned short*)d_ws;                 // 768*768*2 = 1179648 B
    int2* partials = (int2*)((char*)d_ws + 1179648);             // 64 * 8 B

    wtrans_kernel<<<dim3(ND / 64, ND / 64), 256, 0, stream>>>(W, wbt);
    masks_kernel<<<ROWS / 256, 256, 0, stream>>>(padding, regular, seqpair, out_mp, out_mr, out_ms, partials);
    gemm_fused_kernel<<<NCOL * NROW, 256, 0, stream>>>(x, wbt, bias, outc);
    cr_kernel<<<1, 64, 0, stream>>>(partials, out_cr);
}

// Round 6
// 208.992 us; speedup vs baseline: 1.1031x; 1.1031x over previous
//
#include <hip/hip_runtime.h>
#include <hip/hip_bf16.h>

#define NB 16
#define NS 2048
#define ND 768
#define NG 1024
#define ROWS (NB * NG)            // 16384 output rows (b*G + g)

#define BM 64
#define BN 256
#define BK 32
#define NCOL (ND / BN)            // 3 col-strips
#define NROW (ROWS / BM)          // 256 row-bands
#define NT (ND / BK)              // 24 K-tiles

typedef __attribute__((ext_vector_type(8))) __bf16 bf16x8;
typedef __attribute__((ext_vector_type(8))) unsigned short ushort8_t;
typedef __attribute__((ext_vector_type(4))) float f32x4;

__device__ __forceinline__ unsigned short f2bf(float f) {
    unsigned int u = __builtin_bit_cast(unsigned int, f);
    return (unsigned short)((u + 0x7FFFu + ((u >> 16) & 1u)) >> 16);   // RNE
}

__device__ __forceinline__ void gload_lds16(const void* g, void* l) {
    __builtin_amdgcn_global_load_lds((const __attribute__((address_space(1))) unsigned int*)g,
                                     (__attribute__((address_space(3))) unsigned int*)l, 16, 0, 0);
}

__device__ __forceinline__ float fast_tanh(float v) {
    float x = fminf(fmaxf(v, -15.f), 15.f);
    float e = __expf(2.f * x);
    return (e - 1.f) / (e + 1.f);
}

#define VMCNT4   asm volatile("s_waitcnt vmcnt(4)" ::: "memory")
#define LGKMCNT0 asm volatile("s_waitcnt lgkmcnt(0)" ::: "memory")

// ---- transpose-cast 0.5*W (768x768 f32 row-major [k][n]) to bf16 [n][k]
__global__ __launch_bounds__(256) void wtrans_kernel(const float* __restrict__ W,
                                                     unsigned short* __restrict__ Bt) {
    __shared__ float tile[64][65];
    int n0 = blockIdx.x * 64;
    int k0 = blockIdx.y * 64;
    int tx = threadIdx.x & 63;
    int ty = threadIdx.x >> 6;    // 0..3
    #pragma unroll
    for (int i = 0; i < 64; i += 4)
        tile[ty + i][tx] = W[(long)(k0 + ty + i) * ND + n0 + tx];
    __syncthreads();
    #pragma unroll
    for (int i = 0; i < 64; i += 4)
        Bt[(long)(n0 + ty + i) * ND + k0 + tx] = f2bf(0.5f * tile[tx][ty + i]);
}

// ---- fused GEMM: out[g][c] = tanh( sum_k (x[2g][k]+x[2g+1][k]) * (0.5*W)[k][c] + b[c] )
// BM=64 x BN=256, BK=32; 4 waves 1x4, wave tile 64x64 = 4x4 frags of 16x16x32.
// Double-buffered LDS, raw s_barrier + counted vmcnt (T3/T4-lite): A(t+2) reg-prefetch
// stays in flight across the barrier; gloadB(t+1) covered by the compute phase.
// LDS row-major 64B rows with XOR slot swizzle: slot = chunk ^ ((row>>1)&3)
// (applied to B's global source chunk + A's ds_write addr + both frag reads)
// -> max 2-way bank aliasing (free), global coalescing preserved (permute within 64B row).
__global__ __launch_bounds__(256, 3) void gemm_fused_kernel(const float* __restrict__ x,
                                                            const unsigned short* __restrict__ Bt,
                                                            const float* __restrict__ bias,
                                                            float* __restrict__ out) {
    __shared__ unsigned short Al[2][BM * BK];   // 2 x 4 KB
    __shared__ unsigned short Bl[2][BN * BK];   // 2 x 16 KB
    int tid = threadIdx.x;
    int lane = tid & 63;
    int w = tid >> 6;                        // wave = 64-col strip within block
    int r = lane & 15, h = lane >> 4;

    // bijective XCD swizzle: xcd = bid&7 gets bands {xcd, xcd+8, ...}, 3 strips each
    int bid = blockIdx.x;                    // 0..767
    int xcd = bid & 7;
    int s = bid >> 3;                        // 0..95
    int c = s % 3;
    int rb = (s / 3) * 8 + xcd;              // 0..255
    int row0 = rb * BM;
    int col0 = c * BN;

    int b = row0 >> 10;
    long tokrow = (long)b * NS + 2 * (row0 & (NG - 1));

    // A global: thread t -> group row t>>2, k-chunk (t&3)*8 floats (coalesced 128B/quarter)
    const float* ax0 = x + (tokrow + 2 * (tid >> 2)) * ND + (tid & 3) * 8;
    const float* ax1 = ax0 + ND;
    int swz = ((tid & 3) ^ ((tid >> 3) & 3));
    // A ds_write: row t>>2, swizzled slot
    int aw_off = (tid >> 2) * 64 + swz * 16;
    // B global source: row col0 + q*64 + (t>>2), swizzled 16B chunk (same 64B row segment)
    const char* gB = (const char*)Bt + (long)(col0 + (tid >> 2)) * (ND * 2) + swz * 16;

    // fragment read offsets (loop-invariant)
    int aoff[4], boff[4];
    #pragma unroll
    for (int m = 0; m < 4; ++m) {
        int row = m * 16 + r;
        aoff[m] = row * 64 + ((h ^ ((row >> 1) & 3)) * 16);
    }
    #pragma unroll
    for (int n = 0; n < 4; ++n) {
        int row = w * 64 + n * 16 + r;
        boff[n] = row * 64 + ((h ^ ((row >> 1) & 3)) * 16);
    }

    f32x4 acc[4][4] = {};
    float4 a0A, a1A, b0A, b1A, a0B, a1B, b0B, b1B;

#define LOADA(KT, A0, A1, B0, B1) do { \
        const float* p0 = ax0 + (KT) * BK; const float* p1 = ax1 + (KT) * BK; \
        A0 = *(const float4*)p0; B0 = *(const float4*)(p0 + 4); \
        A1 = *(const float4*)p1; B1 = *(const float4*)(p1 + 4); } while (0)

#define GLOADB(KT, CUR) do { \
        const char* gb = gB + (long)(KT) * 64; \
        _Pragma("unroll") \
        for (int q = 0; q < 4; ++q) \
            gload_lds16(gb + (long)q * 64 * (ND * 2), (char*)&Bl[CUR][0] + q * 4096 + tid * 16); } while (0)

#define AWRITE(CUR, A0, A1, B0, B1) do { \
        ushort8_t t8; \
        _Pragma("unroll") \
        for (int e = 0; e < 4; ++e) { t8[e] = f2bf(A0[e] + A1[e]); t8[4 + e] = f2bf(B0[e] + B1[e]); } \
        *(ushort8_t*)((char*)&Al[CUR][0] + aw_off) = t8; } while (0)

#define COMPUTE(CUR) do { \
        bf16x8 af[4]; \
        _Pragma("unroll") \
        for (int m = 0; m < 4; ++m) \
            af[m] = __builtin_bit_cast(bf16x8, *(const ushort8_t*)((const char*)&Al[CUR][0] + aoff[m])); \
        _Pragma("unroll") \
        for (int n = 0; n < 4; ++n) { \
            bf16x8 bv = __builtin_bit_cast(bf16x8, *(const ushort8_t*)((const char*)&Bl[CUR][0] + boff[n])); \
            _Pragma("unroll") \
            for (int m = 0; m < 4; ++m) \
                acc[m][n] = __builtin_amdgcn_mfma_f32_16x16x32_bf16(af[m], bv, acc[m][n], 0, 0, 0); \
        } } while (0)

    // STEP(t, cur): compute tile t from buf cur; stage tile t+1 into cur^1;
    // prefetch A(t+2) regs (stay in flight across barrier: vmcnt(4)).
#define STEP(T, CUR, LA0, LA1, LB0, LB1, UA0, UA1, UB0, UB1) do { \
        int kb = ((T) + 1 < NT) ? (T) + 1 : NT - 1; \
        int ka = ((T) + 2 < NT) ? (T) + 2 : NT - 1; \
        GLOADB(kb, (CUR) ^ 1); \
        LOADA(ka, LA0, LA1, LB0, LB1); \
        COMPUTE(CUR); \
        AWRITE((CUR) ^ 1, UA0, UA1, UB0, UB1);   /* auto vmcnt(8): completes A(t+1) */ \
        VMCNT4;    /* completes gloadB(t+1); A(t+2) stays in flight */ \
        LGKMCNT0;  /* my ds_writes visible */ \
        __builtin_amdgcn_s_barrier(); } while (0)

    // prologue: tile 0 staged, A(1) in flight
    LOADA(0, a0A, a1A, b0A, b1A);
    GLOADB(0, 0);
    AWRITE(0, a0A, a1A, b0A, b1A);           // auto-wait completes A(0), B(0) flying
    LOADA(1, a0B, a1B, b0B, b1B);
    VMCNT4;                                   // B(0) done; A(1) in flight
    LGKMCNT0;
    __builtin_amdgcn_s_barrier();

    #pragma unroll 2
    for (int t = 0; t < NT; t += 2) {
        STEP(t,     0, a0A, a1A, b0A, b1A,  a0B, a1B, b0B, b1B);
        STEP(t + 1, 1, a0B, a1B, b0B, b1B,  a0A, a1A, b0A, b1A);
    }

    float bv[4];
    #pragma unroll
    for (int n = 0; n < 4; ++n) bv[n] = bias[col0 + w * 64 + n * 16 + r];

    #pragma unroll
    for (int m = 0; m < 4; ++m) {
        #pragma unroll
        for (int q = 0; q < 4; ++q) {
            int orow = row0 + m * 16 + h * 4 + q;
            float* op = out + (long)orow * ND + col0 + w * 64 + r;
            #pragma unroll
            for (int n = 0; n < 4; ++n)
                op[n * 16] = fast_tanh(acc[m][n][q] + bv[n]);
        }
    }
#undef LOADA
#undef GLOADB
#undef AWRITE
#undef COMPUTE
#undef STEP
}

// ---- per-group masks + per-block partial sums (no atomics, no pre-zero)
__global__ __launch_bounds__(256) void masks_kernel(const int* __restrict__ padding,
                                                    const int* __restrict__ regular,
                                                    const int* __restrict__ seqpair,
                                                    float* __restrict__ out_mp,
                                                    float* __restrict__ out_mr,
                                                    float* __restrict__ out_ms,
                                                    int2* __restrict__ partials) {
    int i = blockIdx.x * 256 + threadIdx.x;      // over ROWS
    int b = i >> 10, g = i & (NG - 1);
    int t = b * NS + 2 * g;
    int r0 = regular[t], r1 = regular[t + 1];
    int p  = ((padding[t] | padding[t + 1]) != 0) ? 1 : 0;
    int mr = ((r0 | r1) != 0) ? 1 : 0;
    int ms = ((seqpair[t] > 0) && (seqpair[t + 1] > 0)) ? 1 : 0;
    if (p == 0) ms = -1;
    out_mp[i] = (float)p;
    out_mr[i] = (float)mr;
    out_ms[i] = (float)ms;

    int mrs = mr, tok = r0 + r1;
    #pragma unroll
    for (int off = 32; off > 0; off >>= 1) {
        mrs += __shfl_down(mrs, off);
        tok += __shfl_down(tok, off);
    }
    __shared__ int sm[4], st[4];
    int wv = threadIdx.x >> 6, lane = threadIdx.x & 63;
    if (lane == 0) { sm[wv] = mrs; st[wv] = tok; }
    __syncthreads();
    if (threadIdx.x == 0)
        partials[blockIdx.x] = make_int2(sm[0] + sm[1] + sm[2] + sm[3],
                                         st[0] + st[1] + st[2] + st[3]);
}

// ---- compression_rate from 64 per-block partials (single wave)
__global__ void cr_kernel(const int2* __restrict__ partials, float* __restrict__ cr) {
    int2 p = partials[threadIdx.x];
    int a = p.x, t = p.y;
    #pragma unroll
    for (int off = 32; off > 0; off >>= 1) {
        a += __shfl_down(a, off);
        t += __shfl_down(t, off);
    }
    if (threadIdx.x == 0) cr[0] = (float)a / (float)t;
}

extern "C" void kernel_launch(void* const* d_in, const int* in_sizes, int n_in,
                              void* d_out, int out_size, void* d_ws, size_t ws_size,
                              hipStream_t stream) {
    const float* x        = (const float*)d_in[0];
    const int*   padding  = (const int*)d_in[2];
    const int*   regular  = (const int*)d_in[3];
    const int*   seqpair  = (const int*)d_in[4];
    const float* W        = (const float*)d_in[6];
    const float* bias     = (const float*)d_in[7];

    float* outc   = (float*)d_out;                       // compact (B,G,D)
    float* out_mp = outc + (long)ROWS * ND;              // mask_padding (B,G)
    float* out_mr = out_mp + ROWS;                       // mask_regular (B,G)
    float* out_ms = out_mr + ROWS;                       // mask_seq_pair (B,G)
    float* out_cr = out_ms + ROWS;                       // compression_rate (1)

    unsigned short* wbt = (unsigned short*)d_ws;                 // 768*768*2 = 1179648 B
    int2* partials = (int2*)((char*)d_ws + 1179648);             // 64 * 8 B

    wtrans_kernel<<<dim3(ND / 64, ND / 64), 256, 0, stream>>>(W, wbt);
    masks_kernel<<<ROWS / 256, 256, 0, stream>>>(padding, regular, seqpair, out_mp, out_mr, out_ms, partials);
    gemm_fused_kernel<<<NCOL * NROW, 256, 0, stream>>>(x, wbt, bias, outc);
    cr_kernel<<<1, 64, 0, stream>>>(partials, out_cr);
}